// Round 2
// baseline (868.265 us; speedup 1.0000x reference)
//
#include <hip/hip_runtime.h>
#include <hip/hip_bf16.h>
#include <stdint.h>

// ---------- types ----------
typedef _Float16 half8 __attribute__((ext_vector_type(8)));
typedef float floatx4 __attribute__((ext_vector_type(4)));

#define MFMA16(a, b, c) __builtin_amdgcn_mfma_f32_16x16x32_f16(a, b, c, 0, 0, 0)

// async global->LDS, 16B per lane, dest = wave-uniform base + lane*16
__device__ __forceinline__ void async_load16(const void* g, void* l) {
    __builtin_amdgcn_global_load_lds((__attribute__((address_space(1))) void*)(g),
                                     (__attribute__((address_space(3))) void*)(l),
                                     16, 0, 0);
}

// ---------- fp32 -> fp16 conversion (with optional scale) ----------
__global__ __launch_bounds__(256) void cvt_kernel(const float* __restrict__ in,
                                                  _Float16* __restrict__ out,
                                                  int n, float scale) {
    int i = (blockIdx.x * 256 + threadIdx.x) * 8;
    if (i >= n) return;
    float4 v0 = *(const float4*)(in + i);
    float4 v1 = *(const float4*)(in + i + 4);
    half8 h;
    h[0] = (_Float16)(v0.x * scale);
    h[1] = (_Float16)(v0.y * scale);
    h[2] = (_Float16)(v0.z * scale);
    h[3] = (_Float16)(v0.w * scale);
    h[4] = (_Float16)(v1.x * scale);
    h[5] = (_Float16)(v1.y * scale);
    h[6] = (_Float16)(v1.z * scale);
    h[7] = (_Float16)(v1.w * scale);
    *(half8*)(out + i) = h;
}

// ---------- C[m][n] = sum_k A[m][k] * B[n][k]  (both row-major, k contiguous) ----------
// 128x128 tile, BK=32, 256 threads = 4 waves in 2x2, each wave 64x64 (4x4 MFMA tiles)
__global__ __launch_bounds__(256) void gemm_bt(const _Float16* __restrict__ A,
                                               const _Float16* __restrict__ B,
                                               _Float16* __restrict__ C,
                                               int M, int N, int K) {
    __shared__ _Float16 sA[128 * 32];   // 8 KB, row-major [128][32]
    __shared__ _Float16 sB[128 * 32];
    const int tid  = threadIdx.x;
    const int lane = tid & 63;
    const int w    = tid >> 6;
    const int quad = lane >> 4;
    const int m16  = lane & 15;
    const int wm   = (w >> 1) << 6;   // wave row offset in tile
    const int wn   = (w & 1) << 6;    // wave col offset
    const long row0 = (long)blockIdx.y * 128;
    const long col0 = (long)blockIdx.x * 128;

    floatx4 acc[4][4] = {};

    // staging: LDS flat byte offset tid*16 <-> row tid>>2, colbyte (tid&3)*16
    const _Float16* ga0 = A + (row0 + (tid >> 2)) * (long)K + (tid & 3) * 8;
    const _Float16* ga1 = ga0 + 64l * K;
    const _Float16* gb0 = B + (col0 + (tid >> 2)) * (long)K + (tid & 3) * 8;
    const _Float16* gb1 = gb0 + 64l * K;
    char* lA = (char*)sA + (tid & 0xC0) * 16;   // wave-uniform base (w*1024)
    char* lB = (char*)sB + (tid & 0xC0) * 16;

    for (int k0 = 0; k0 < K; k0 += 32) {
        async_load16(ga0, lA);
        async_load16(ga1, lA + 4096);
        async_load16(gb0, lB);
        async_load16(gb1, lB + 4096);
        ga0 += 32; ga1 += 32; gb0 += 32; gb1 += 32;
        __syncthreads();   // drains vmcnt(0) before barrier

        half8 af[4], bf[4];
#pragma unroll
        for (int mt = 0; mt < 4; mt++)
            af[mt] = *(const half8*)(sA + (wm + mt * 16 + m16) * 32 + quad * 8);
#pragma unroll
        for (int nt = 0; nt < 4; nt++)
            bf[nt] = *(const half8*)(sB + (wn + nt * 16 + m16) * 32 + quad * 8);
#pragma unroll
        for (int mt = 0; mt < 4; mt++)
#pragma unroll
            for (int nt = 0; nt < 4; nt++)
                acc[mt][nt] = MFMA16(af[mt], bf[nt], acc[mt][nt]);
        __syncthreads();
    }

    // epilogue: C/D layout col=lane&15, row=quad*4+reg  [m89-verified]
#pragma unroll
    for (int mt = 0; mt < 4; mt++)
#pragma unroll
        for (int nt = 0; nt < 4; nt++)
#pragma unroll
            for (int reg = 0; reg < 4; reg++) {
                long r = row0 + wm + mt * 16 + quad * 4 + reg;
                long c = col0 + wn + nt * 16 + m16;
                C[r * N + c] = (_Float16)acc[mt][nt][reg];
            }
}

// ---------- banded attention ----------
// one block = 16 query rows of one batch; 4 waves.
// Phase A: waves split key-tiles, scores -> LDS (fp32, band-masked)
// Phase B: row softmax in LDS, P -> LDS fp16
// Phase C: waves split D (256 cols each), O = P*V from Vt, scale by 1/l
#define SS_STRIDE 548   // fp32
#define SP_STRIDE 552   // fp16
__global__ __launch_bounds__(256) void attn_kernel(const _Float16* __restrict__ Qh,
                                                   const _Float16* __restrict__ Kh,
                                                   const _Float16* __restrict__ Vt,
                                                   float* __restrict__ out) {
    const int S = 4096, D = 1024, TOK = 16384;
    __shared__ float    sS[16 * SS_STRIDE];
    __shared__ _Float16 sP[16 * SP_STRIDE];
    __shared__ float    sInv[16];

    const int tid  = threadIdx.x;
    const int lane = tid & 63;
    const int w    = tid >> 6;
    const int quad = lane >> 4;
    const int c16  = lane & 15;
    const int b    = blockIdx.x >> 8;          // 256 q-tiles per batch
    const int q0   = (blockIdx.x & 255) << 4;

    // key range aligned to 32 so L % 32 == 0 (extra keys killed by band mask)
    int kstart = (q0 - 256) & ~31; if (kstart < 0) kstart = 0;
    int kend   = (q0 + 272 + 31) & ~31; if (kend > S) kend = S;
    const int L = kend - kstart;          // <= 544
    const int ntiles = L >> 4;            // <= 34

    // ---- Phase A: scores = Q K^T (Q pre-scaled by 1/sqrt(D)) ----
    {
        const _Float16* qptr = Qh + (long)(b * S + q0 + c16) * D + quad * 8;
        floatx4 acc[9] = {};
        const _Float16* kptr[9];
#pragma unroll
        for (int i = 0; i < 9; i++) {
            int t = w + i * 4;
            int tc = (t < ntiles) ? t : 0;
            kptr[i] = Kh + (long)(b * S + kstart + tc * 16 + c16) * D + quad * 8;
        }
        for (int kc = 0; kc < 1024; kc += 32) {
            half8 aQ = *(const half8*)(qptr + kc);
#pragma unroll
            for (int i = 0; i < 9; i++) {
                if (w + i * 4 < ntiles) {   // wave-uniform
                    half8 bK = *(const half8*)(kptr[i] + kc);
                    acc[i] = MFMA16(aQ, bK, acc[i]);
                }
            }
        }
#pragma unroll
        for (int i = 0; i < 9; i++) {
            int t = w + i * 4;
            if (t < ntiles) {
                int col = t * 16 + c16;
                int j   = kstart + col;
#pragma unroll
                for (int reg = 0; reg < 4; reg++) {
                    int r  = quad * 4 + reg;
                    int qi = q0 + r;
                    int dd = qi - j; if (dd < 0) dd = -dd;
                    sS[r * SS_STRIDE + col] = (dd <= 256) ? acc[i][reg] : -1e30f;
                }
            }
        }
    }
    __syncthreads();

    // ---- Phase B: softmax per row (16 threads per row, wave-aligned groups) ----
    {
        const int r = tid >> 4;
        const int k = tid & 15;
        const float* row = sS + r * SS_STRIDE;
        float mx = -1e30f;
        for (int c = k; c < L; c += 16) mx = fmaxf(mx, row[c]);
#pragma unroll
        for (int off = 8; off; off >>= 1) mx = fmaxf(mx, __shfl_xor(mx, off, 16));
        float sum = 0.f;
        _Float16* prow = sP + r * SP_STRIDE;
        for (int c = k; c < L; c += 16) {
            float e = __expf(row[c] - mx);   // masked: exp(-1e30 - mx) == 0
            prow[c] = (_Float16)e;
            sum += e;
        }
#pragma unroll
        for (int off = 8; off; off >>= 1) sum += __shfl_xor(sum, off, 16);
        if (k == 0) sInv[r] = 1.f / sum;
    }
    __syncthreads();

    // ---- Phase C: O = P V, wave w owns D cols [256w, 256w+256) ----
    {
        const int dbase = w << 8;
        floatx4 oacc[16] = {};
        const _Float16* pptr = sP + c16 * SP_STRIDE + quad * 8;            // A-op: m=lane&15, k=quad*8+j
        const _Float16* vptr = Vt + (long)(dbase + c16) * TOK + b * S + kstart + quad * 8; // B-op from Vt rows
        for (int lc = 0; lc < L; lc += 32) {
            half8 aP = *(const half8*)(pptr + lc);
#pragma unroll
            for (int nt = 0; nt < 16; nt++) {
                half8 bV = *(const half8*)(vptr + (long)nt * 16 * TOK + lc);
                oacc[nt] = MFMA16(aP, bV, oacc[nt]);
            }
        }
        const long obase = (long)(b * S + q0) * D;
#pragma unroll
        for (int nt = 0; nt < 16; nt++) {
            int c = dbase + nt * 16 + c16;
#pragma unroll
            for (int reg = 0; reg < 4; reg++) {
                int r = quad * 4 + reg;
                out[obase + (long)r * D + c] = oacc[nt][reg] * sInv[r];
            }
        }
    }
}

extern "C" void kernel_launch(void* const* d_in, const int* in_sizes, int n_in,
                              void* d_out, int out_size, void* d_ws, size_t ws_size,
                              hipStream_t stream) {
    const float* X  = (const float*)d_in[0];
    const float* Y  = (const float*)d_in[1];
    const float* Wq = (const float*)d_in[2];
    const float* Wk = (const float*)d_in[3];
    const float* Wv = (const float*)d_in[4];
    float* out = (float*)d_out;

    const long NTOK = 16384, D = 1024;
    // workspace layout (fp16). Kh aliases Yh: Yh is only read by the Q-projection,
    // which completes (stream-ordered) before the K-projection writes Kh.
    char* p = (char*)d_ws;
    _Float16* Xh  = (_Float16*)p; p += NTOK * D * 2;   // 32 MB
    _Float16* Yh  = (_Float16*)p; p += NTOK * D * 2;   // 32 MB (reused as Kh)
    _Float16* Wqh = (_Float16*)p; p += D * D * 2;      //  2 MB (pre-scaled by 1/32)
    _Float16* Wkh = (_Float16*)p; p += D * D * 2;
    _Float16* Wvh = (_Float16*)p; p += D * D * 2;
    _Float16* Qh  = (_Float16*)p; p += NTOK * D * 2;   // 32 MB
    _Float16* Vt  = (_Float16*)p; p += NTOK * D * 2;   // 32 MB  [D][NTOK]
    _Float16* Kh  = Yh;

    const int nT = (int)(NTOK * D);   // 16,777,216
    const int nW = (int)(D * D);      //  1,048,576
    cvt_kernel<<<nT / 2048, 256, 0, stream>>>(X, Xh, nT, 1.f);
    cvt_kernel<<<nT / 2048, 256, 0, stream>>>(Y, Yh, nT, 1.f);
    cvt_kernel<<<nW / 2048, 256, 0, stream>>>(Wq, Wqh, nW, 0.03125f);  // fold 1/sqrt(1024)
    cvt_kernel<<<nW / 2048, 256, 0, stream>>>(Wk, Wkh, nW, 1.f);
    cvt_kernel<<<nW / 2048, 256, 0, stream>>>(Wv, Wvh, nW, 1.f);

    // Q = Y Wq^T (scaled), K = X Wk^T, Vt = Wv X^T  -- all same B^T GEMM
    gemm_bt<<<dim3(1024 / 128, 16384 / 128), 256, 0, stream>>>(Yh, Wqh, Qh, 16384, 1024, 1024);
    gemm_bt<<<dim3(1024 / 128, 16384 / 128), 256, 0, stream>>>(Xh, Wkh, Kh, 16384, 1024, 1024);
    gemm_bt<<<dim3(16384 / 128, 1024 / 128), 256, 0, stream>>>(Wvh, Xh, Vt, 1024, 16384, 1024);

    attn_kernel<<<dim3(1024), 256, 0, stream>>>(Qh, Kh, Vt, out);
}

// Round 3
// 681.378 us; speedup vs baseline: 1.2743x; 1.2743x over previous
//
#include <hip/hip_runtime.h>
#include <hip/hip_bf16.h>
#include <stdint.h>

// ---------- types ----------
typedef _Float16 half8 __attribute__((ext_vector_type(8)));
typedef float floatx4 __attribute__((ext_vector_type(4)));

#define MFMA16(a, b, c) __builtin_amdgcn_mfma_f32_16x16x32_f16(a, b, c, 0, 0, 0)

// async global->LDS, 16B per lane, dest = wave-uniform base + lane*16
__device__ __forceinline__ void async_load16(const void* g, void* l) {
    __builtin_amdgcn_global_load_lds((__attribute__((address_space(1))) void*)(g),
                                     (__attribute__((address_space(3))) void*)(l),
                                     16, 0, 0);
}

// ---------- fp32 -> fp16 conversion (with optional scale) ----------
__global__ __launch_bounds__(256) void cvt_kernel(const float* __restrict__ in,
                                                  _Float16* __restrict__ out,
                                                  int n, float scale) {
    int i = (blockIdx.x * 256 + threadIdx.x) * 8;
    if (i >= n) return;
    float4 v0 = *(const float4*)(in + i);
    float4 v1 = *(const float4*)(in + i + 4);
    half8 h;
    h[0] = (_Float16)(v0.x * scale);
    h[1] = (_Float16)(v0.y * scale);
    h[2] = (_Float16)(v0.z * scale);
    h[3] = (_Float16)(v0.w * scale);
    h[4] = (_Float16)(v1.x * scale);
    h[5] = (_Float16)(v1.y * scale);
    h[6] = (_Float16)(v1.z * scale);
    h[7] = (_Float16)(v1.w * scale);
    *(half8*)(out + i) = h;
}

// ---------- C[m][n] = sum_k A[m][k] * B[n][k]  (both row-major, k contiguous) ----------
// 128x128 tile, BK=32, 256 threads = 4 waves in 2x2, each wave 64x64 (4x4 MFMA tiles)
__global__ __launch_bounds__(256) void gemm_bt(const _Float16* __restrict__ A,
                                               const _Float16* __restrict__ B,
                                               _Float16* __restrict__ C,
                                               int M, int N, int K) {
    __shared__ _Float16 sA[128 * 32];   // 8 KB, row-major [128][32]
    __shared__ _Float16 sB[128 * 32];
    const int tid  = threadIdx.x;
    const int lane = tid & 63;
    const int w    = tid >> 6;
    const int quad = lane >> 4;
    const int m16  = lane & 15;
    const int wm   = (w >> 1) << 6;   // wave row offset in tile
    const int wn   = (w & 1) << 6;    // wave col offset
    const long row0 = (long)blockIdx.y * 128;
    const long col0 = (long)blockIdx.x * 128;

    floatx4 acc[4][4] = {};

    const _Float16* ga0 = A + (row0 + (tid >> 2)) * (long)K + (tid & 3) * 8;
    const _Float16* ga1 = ga0 + 64l * K;
    const _Float16* gb0 = B + (col0 + (tid >> 2)) * (long)K + (tid & 3) * 8;
    const _Float16* gb1 = gb0 + 64l * K;
    char* lA = (char*)sA + (tid & 0xC0) * 16;   // wave-uniform base (w*1024)
    char* lB = (char*)sB + (tid & 0xC0) * 16;

    for (int k0 = 0; k0 < K; k0 += 32) {
        async_load16(ga0, lA);
        async_load16(ga1, lA + 4096);
        async_load16(gb0, lB);
        async_load16(gb1, lB + 4096);
        ga0 += 32; ga1 += 32; gb0 += 32; gb1 += 32;
        __syncthreads();

        half8 af[4], bf[4];
#pragma unroll
        for (int mt = 0; mt < 4; mt++)
            af[mt] = *(const half8*)(sA + (wm + mt * 16 + m16) * 32 + quad * 8);
#pragma unroll
        for (int nt = 0; nt < 4; nt++)
            bf[nt] = *(const half8*)(sB + (wn + nt * 16 + m16) * 32 + quad * 8);
#pragma unroll
        for (int mt = 0; mt < 4; mt++)
#pragma unroll
            for (int nt = 0; nt < 4; nt++)
                acc[mt][nt] = MFMA16(af[mt], bf[nt], acc[mt][nt]);
        __syncthreads();
    }

#pragma unroll
    for (int mt = 0; mt < 4; mt++)
#pragma unroll
        for (int nt = 0; nt < 4; nt++)
#pragma unroll
            for (int reg = 0; reg < 4; reg++) {
                long r = row0 + wm + mt * 16 + quad * 4 + reg;
                long c = col0 + wn + nt * 16 + m16;
                C[r * N + c] = (_Float16)acc[mt][nt][reg];
            }
}

// ---------- banded attention, T=64 queries/block, 512 threads (8 waves) ----------
// Phase A: wave w (row-group rg=w&3, band-half h=w>>2) computes S for its 16 rows x
//          its half of the band tiles IN REGISTERS (<=18 tiles, 72 VGPRs), masks,
//          reduces row max/sum via quad shuffles + tiny LDS combine, writes P fp16
//          to LDS in MFMA-A layout.
// Phase B: wave w (col-block cb=w&3, 256 cols; 2 row-groups sequentially) computes
//          O = P*V from Vt, scales by 1/l, stores fp32.
#define SPS 584   // P stride in halves: 584*2B = 1168B = 292 dwords, 292%32==4 -> balanced banks
__global__ __launch_bounds__(512, 2) void attn_kernel(const _Float16* __restrict__ Qh,
                                                      const _Float16* __restrict__ Kh,
                                                      const _Float16* __restrict__ Vt,
                                                      float* __restrict__ out) {
    const int S = 4096, D = 1024, TOK = 16384;
    __shared__ _Float16 sP[64 * SPS];   // 74752 B
    __shared__ float sMax[64][2];
    __shared__ float sSum[64][2];

    const int tid  = threadIdx.x;
    const int lane = tid & 63;
    const int w    = tid >> 6;
    const int quad = lane >> 4;
    const int c16  = lane & 15;
    const int b    = blockIdx.x >> 6;          // 64 q-tiles per batch
    const int q0   = (blockIdx.x & 63) << 6;

    int kstart = q0 - 256; if (kstart < 0) kstart = 0;   // q0 mult of 64 -> aligned
    int kend   = q0 + 320; if (kend > S) kend = S;       // mult of 32
    const int L = kend - kstart;       // <= 576, multiple of 32
    const int ntiles = L >> 4;         // <= 36

    const int rg = w & 3;              // Phase A row group
    const int h  = w >> 2;             // Phase A band half (tiles t = 2i+h)
    const int rows0 = rg << 4;

    floatx4 acc[18] = {};              // S accumulators: 72 VGPRs

    // ---- Phase A: S = Q K^T for 16 rows x half band (Q pre-scaled by 1/sqrt(D)) ----
    {
        const _Float16* qptr = Qh + (long)(b * S + q0 + rows0 + c16) * D + quad * 8;
        const _Float16* kbase = Kh + (long)(b * S + kstart) * D + quad * 8;
        for (int kc = 0; kc < 1024; kc += 32) {
            half8 aQ = *(const half8*)(qptr + kc);
#pragma unroll
            for (int i = 0; i < 18; i++) {
                int t = 2 * i + h;
                if (t < ntiles) {      // wave-uniform
                    half8 bK = *(const half8*)(kbase + (long)(t * 16 + c16) * D + kc);
                    acc[i] = MFMA16(aQ, bK, acc[i]);
                }
            }
        }
        // band mask (before max!)
#pragma unroll
        for (int i = 0; i < 18; i++) {
            int t = 2 * i + h;
            if (t < ntiles) {
                int j = kstart + t * 16 + c16;
#pragma unroll
                for (int r = 0; r < 4; r++) {
                    int qi = q0 + rows0 + quad * 4 + r;
                    int dd = qi - j; dd = dd < 0 ? -dd : dd;
                    if (dd > 256) acc[i][r] = -1e30f;
                }
            }
        }
        // partial row max over this half, reduce across the 16-lane quad group
#pragma unroll
        for (int r = 0; r < 4; r++) {
            float m = -1e30f;
#pragma unroll
            for (int i = 0; i < 18; i++)
                if (2 * i + h < ntiles) m = fmaxf(m, acc[i][r]);
#pragma unroll
            for (int off = 1; off < 16; off <<= 1) m = fmaxf(m, __shfl_xor(m, off, 64));
            if (c16 == 0) sMax[rows0 + quad * 4 + r][h] = m;
        }
    }
    __syncthreads();

    // ---- exp, partial sums, P -> LDS ----
    {
#pragma unroll
        for (int r = 0; r < 4; r++) {
            int row = rows0 + quad * 4 + r;
            float fm = fmaxf(sMax[row][0], sMax[row][1]);
            float s = 0.f;
#pragma unroll
            for (int i = 0; i < 18; i++) {
                int t = 2 * i + h;
                if (t < ntiles) {
                    float e = __expf(acc[i][r] - fm);   // masked: exp(-1e30-fm)==0
                    s += e;
                    sP[row * SPS + t * 16 + c16] = (_Float16)e;
                }
            }
#pragma unroll
            for (int off = 1; off < 16; off <<= 1) s += __shfl_xor(s, off, 64);
            if (c16 == 0) sSum[row][h] = s;
        }
    }
    __syncthreads();

    // ---- Phase B: O = P V, wave w: col block 256*(w&3), row groups (w>>2), (w>>2)+2 ----
    {
        const int dbase = (w & 3) << 8;
        const int nsteps = L >> 5;     // <= 18
        const _Float16* vbase = Vt + (long)(dbase + c16) * TOK + b * S + kstart + quad * 8;
#pragma unroll
        for (int gg = 0; gg < 2; gg++) {
            const int g = (w >> 2) + gg * 2;
            floatx4 oacc[16] = {};
            const _Float16* pbase = sP + (g * 16 + c16) * SPS + quad * 8;
            for (int s = 0; s < nsteps; s++) {
                half8 aP = *(const half8*)(pbase + 32 * s);
#pragma unroll
                for (int nt = 0; nt < 16; nt++) {
                    half8 bV = *(const half8*)(vbase + (long)nt * 16 * TOK + 32 * s);
                    oacc[nt] = MFMA16(aP, bV, oacc[nt]);
                }
            }
#pragma unroll
            for (int r = 0; r < 4; r++) {
                int row = g * 16 + quad * 4 + r;
                float inv = 1.f / (sSum[row][0] + sSum[row][1]);
                long obase = (long)(b * S + q0 + row) * D;
#pragma unroll
                for (int nt = 0; nt < 16; nt++)
                    out[obase + dbase + nt * 16 + c16] = oacc[nt][r] * inv;
            }
        }
    }
}

extern "C" void kernel_launch(void* const* d_in, const int* in_sizes, int n_in,
                              void* d_out, int out_size, void* d_ws, size_t ws_size,
                              hipStream_t stream) {
    const float* X  = (const float*)d_in[0];
    const float* Y  = (const float*)d_in[1];
    const float* Wq = (const float*)d_in[2];
    const float* Wk = (const float*)d_in[3];
    const float* Wv = (const float*)d_in[4];
    float* out = (float*)d_out;

    const long NTOK = 16384, D = 1024;
    // workspace layout (fp16). Kh aliases Yh: Yh is only read by the Q-projection,
    // which completes (stream-ordered) before the K-projection writes Kh.
    char* p = (char*)d_ws;
    _Float16* Xh  = (_Float16*)p; p += NTOK * D * 2;   // 32 MB
    _Float16* Yh  = (_Float16*)p; p += NTOK * D * 2;   // 32 MB (reused as Kh)
    _Float16* Wqh = (_Float16*)p; p += D * D * 2;      //  2 MB (pre-scaled by 1/32)
    _Float16* Wkh = (_Float16*)p; p += D * D * 2;
    _Float16* Wvh = (_Float16*)p; p += D * D * 2;
    _Float16* Qh  = (_Float16*)p; p += NTOK * D * 2;   // 32 MB
    _Float16* Vt  = (_Float16*)p; p += NTOK * D * 2;   // 32 MB  [D][NTOK]
    _Float16* Kh  = Yh;

    const int nT = (int)(NTOK * D);   // 16,777,216
    const int nW = (int)(D * D);      //  1,048,576
    cvt_kernel<<<nT / 2048, 256, 0, stream>>>(X, Xh, nT, 1.f);
    cvt_kernel<<<nT / 2048, 256, 0, stream>>>(Y, Yh, nT, 1.f);
    cvt_kernel<<<nW / 2048, 256, 0, stream>>>(Wq, Wqh, nW, 0.03125f);  // fold 1/sqrt(1024)
    cvt_kernel<<<nW / 2048, 256, 0, stream>>>(Wk, Wkh, nW, 1.f);
    cvt_kernel<<<nW / 2048, 256, 0, stream>>>(Wv, Wvh, nW, 1.f);

    // Q = Y Wq^T (scaled), K = X Wk^T, Vt = Wv X^T  -- all same B^T GEMM
    gemm_bt<<<dim3(1024 / 128, 16384 / 128), 256, 0, stream>>>(Yh, Wqh, Qh, 16384, 1024, 1024);
    gemm_bt<<<dim3(1024 / 128, 16384 / 128), 256, 0, stream>>>(Xh, Wkh, Kh, 16384, 1024, 1024);
    gemm_bt<<<dim3(16384 / 128, 1024 / 128), 256, 0, stream>>>(Wvh, Xh, Vt, 1024, 16384, 1024);

    attn_kernel<<<dim3(256), 512, 0, stream>>>(Qh, Kh, Vt, out);
}

// Round 4
// 476.319 us; speedup vs baseline: 1.8229x; 1.4305x over previous
//
#include <hip/hip_runtime.h>
#include <hip/hip_bf16.h>
#include <stdint.h>

// ---------- types ----------
typedef _Float16 half8 __attribute__((ext_vector_type(8)));
typedef float floatx4 __attribute__((ext_vector_type(4)));

#define MFMA16(a, b, c) __builtin_amdgcn_mfma_f32_16x16x32_f16(a, b, c, 0, 0, 0)

// async global->LDS, 16B per lane, dest = wave-uniform base + lane*16
__device__ __forceinline__ void async_load16(const void* g, void* l) {
    __builtin_amdgcn_global_load_lds((__attribute__((address_space(1))) void*)(g),
                                     (__attribute__((address_space(3))) void*)(l),
                                     16, 0, 0);
}

// ---------- fp32 -> fp16 conversion (with optional scale) ----------
__global__ __launch_bounds__(256) void cvt_kernel(const float* __restrict__ in,
                                                  _Float16* __restrict__ out,
                                                  int n, float scale) {
    int i = (blockIdx.x * 256 + threadIdx.x) * 8;
    if (i >= n) return;
    float4 v0 = *(const float4*)(in + i);
    float4 v1 = *(const float4*)(in + i + 4);
    half8 h;
    h[0] = (_Float16)(v0.x * scale);
    h[1] = (_Float16)(v0.y * scale);
    h[2] = (_Float16)(v0.z * scale);
    h[3] = (_Float16)(v0.w * scale);
    h[4] = (_Float16)(v1.x * scale);
    h[5] = (_Float16)(v1.y * scale);
    h[6] = (_Float16)(v1.z * scale);
    h[7] = (_Float16)(v1.w * scale);
    *(half8*)(out + i) = h;
}

// ---------- C[m][n] = sum_k A[m][k] * B[n][k] ----------
// 128x128 tile, BK=32, 4 waves; double-buffered LDS, ONE barrier per k-chunk,
// prefetch issued after the barrier so it overlaps MFMA (drain happens next iter).
__global__ __launch_bounds__(256) void gemm_bt(const _Float16* __restrict__ A,
                                               const _Float16* __restrict__ B,
                                               _Float16* __restrict__ C,
                                               int M, int N, int K) {
    __shared__ _Float16 sA[2][128 * 32];   // 2 x 8 KB
    __shared__ _Float16 sB[2][128 * 32];
    const int tid  = threadIdx.x;
    const int lane = tid & 63;
    const int w    = tid >> 6;
    const int quad = lane >> 4;
    const int m16  = lane & 15;
    const int wm   = (w >> 1) << 6;
    const int wn   = (w & 1) << 6;
    const long row0 = (long)blockIdx.y * 128;
    const long col0 = (long)blockIdx.x * 128;

    floatx4 acc[4][4] = {};

    const _Float16* ga0 = A + (row0 + (tid >> 2)) * (long)K + (tid & 3) * 8;
    const _Float16* ga1 = ga0 + 64l * K;
    const _Float16* gb0 = B + (col0 + (tid >> 2)) * (long)K + (tid & 3) * 8;
    const _Float16* gb1 = gb0 + 64l * K;
    const int wchunk = (tid & 0xC0) * 16;   // wave-uniform byte base

    auto stage = [&](int bi, int kc) {
        char* lA = (char*)sA[bi] + wchunk;
        char* lB = (char*)sB[bi] + wchunk;
        async_load16(ga0 + kc, lA);
        async_load16(ga1 + kc, lA + 4096);
        async_load16(gb0 + kc, lB);
        async_load16(gb1 + kc, lB + 4096);
    };

    stage(0, 0);
    for (int kc = 0; kc < K; kc += 32) {
        const int bi = (kc >> 5) & 1;
        __syncthreads();                    // drains prefetch of THIS chunk
        if (kc + 32 < K) stage(bi ^ 1, kc + 32);
        half8 af[4], bf[4];
#pragma unroll
        for (int mt = 0; mt < 4; mt++)
            af[mt] = *(const half8*)(sA[bi] + (wm + mt * 16 + m16) * 32 + quad * 8);
#pragma unroll
        for (int nt = 0; nt < 4; nt++)
            bf[nt] = *(const half8*)(sB[bi] + (wn + nt * 16 + m16) * 32 + quad * 8);
#pragma unroll
        for (int mt = 0; mt < 4; mt++)
#pragma unroll
            for (int nt = 0; nt < 4; nt++)
                acc[mt][nt] = MFMA16(af[mt], bf[nt], acc[mt][nt]);
    }

#pragma unroll
    for (int mt = 0; mt < 4; mt++)
#pragma unroll
        for (int nt = 0; nt < 4; nt++)
#pragma unroll
            for (int reg = 0; reg < 4; reg++) {
                long r = row0 + wm + mt * 16 + quad * 4 + reg;
                long c = col0 + wn + nt * 16 + m16;
                C[r * N + c] = (_Float16)acc[mt][nt][reg];
            }
}

// ---------- attention kernel A: banded S = Q K^T -> softmax -> P (fp16) ----------
// block = 64 q-rows, 512 threads / 8 waves. Whole K band chunk staged in LDS.
// wave w: all 4 row-tiles x band-eighth (tiles t = w + 8i). acc[4][5] = 80 VGPR.
__global__ __launch_bounds__(512) void qk_kernel(const _Float16* __restrict__ Qh,
                                                 const _Float16* __restrict__ Kh,
                                                 _Float16* __restrict__ Pg,
                                                 float* __restrict__ invSum) {
    const int S = 4096, D = 1024;
    __shared__ _Float16 sK[2][576 * 32];   // 2 x 36 KB
    __shared__ _Float16 sQ[2][64 * 32];    // 2 x 4 KB
    __shared__ float sMax[64][8];
    __shared__ float sSum[64][8];

    const int tid  = threadIdx.x;
    const int lane = tid & 63;
    const int w    = tid >> 6;
    const int quad = lane >> 4;
    const int c16  = lane & 15;
    const int qblk = blockIdx.x;
    const int b    = qblk >> 6;
    const int q0   = (qblk & 63) << 6;

    int kstart = q0 - 256; if (kstart < 0) kstart = 0;   // multiple of 64
    int kend   = q0 + 320; if (kend > S) kend = S;       // multiple of 64
    const int L = kend - kstart;        // 320..576, multiple of 64
    const int ntiles = L >> 4;          // <= 36

    const int lrow = lane >> 2;         // 0..15
    const int lcol = (lane & 3) * 8;    // halves
    const _Float16* Kbase = Kh + ((long)(b * S + kstart) + lrow) * D + lcol;
    const _Float16* Qbase = Qh + ((long)(b * S + q0) + w * 16 + lrow) * D + lcol;

    auto stage = [&](int bi, int kc) {
#pragma unroll
        for (int j = 0; j < 5; j++) {
            int g = j * 8 + w;                       // 16-row group, wave-uniform
            if (g < ntiles)
                async_load16(Kbase + (long)g * 16 * D + kc, (char*)sK[bi] + g * 1024);
        }
        if (w < 4)
            async_load16(Qbase + kc, (char*)sQ[bi] + w * 1024);
    };

    floatx4 acc[4][5] = {};
    stage(0, 0);
    for (int kc = 0; kc < 1024; kc += 32) {
        const int bi = (kc >> 5) & 1;
        __syncthreads();
        if (kc + 32 < 1024) stage(bi ^ 1, kc + 32);
        half8 aQ[4];
#pragma unroll
        for (int mt = 0; mt < 4; mt++)
            aQ[mt] = *(const half8*)(sQ[bi] + (mt * 16 + c16) * 32 + quad * 8);
#pragma unroll
        for (int i = 0; i < 5; i++) {
            int t = w + i * 8;
            if (t < ntiles) {                        // wave-uniform
                half8 bK = *(const half8*)(sK[bi] + (t * 16 + c16) * 32 + quad * 8);
#pragma unroll
                for (int mt = 0; mt < 4; mt++)
                    acc[mt][i] = MFMA16(aQ[mt], bK, acc[mt][i]);
            }
        }
    }

    // band mask
#pragma unroll
    for (int i = 0; i < 5; i++) {
        int t = w + i * 8;
        if (t < ntiles) {
            int j = kstart + t * 16 + c16;
#pragma unroll
            for (int mt = 0; mt < 4; mt++)
#pragma unroll
                for (int r = 0; r < 4; r++) {
                    int qi = q0 + mt * 16 + quad * 4 + r;
                    int dd = qi - j; dd = dd < 0 ? -dd : dd;
                    if (dd > 256) acc[mt][i][r] = -1e30f;
                }
        }
    }
    // partial row max (this wave's band-eighth), reduce over the 16-lane col group
#pragma unroll
    for (int mt = 0; mt < 4; mt++)
#pragma unroll
        for (int r = 0; r < 4; r++) {
            float m = -1e30f;
#pragma unroll
            for (int i = 0; i < 5; i++)
                if (w + i * 8 < ntiles) m = fmaxf(m, acc[mt][i][r]);
#pragma unroll
            for (int off = 1; off < 16; off <<= 1) m = fmaxf(m, __shfl_xor(m, off, 64));
            if (c16 == 0) sMax[mt * 16 + quad * 4 + r][w] = m;
        }
    __syncthreads();
    if (tid < 64) {
        float fm = sMax[tid][0];
#pragma unroll
        for (int j = 1; j < 8; j++) fm = fmaxf(fm, sMax[tid][j]);
        sMax[tid][0] = fm;
    }
    __syncthreads();
    // exp, write P, partial sums
#pragma unroll
    for (int mt = 0; mt < 4; mt++)
#pragma unroll
        for (int r = 0; r < 4; r++) {
            int row = mt * 16 + quad * 4 + r;
            float fm = sMax[row][0];
            float s = 0.f;
#pragma unroll
            for (int i = 0; i < 5; i++) {
                int t = w + i * 8;
                if (t < ntiles) {
                    float e = __expf(acc[mt][i][r] - fm);   // masked -> 0
                    s += e;
                    Pg[(long)qblk * 36864 + row * 576 + t * 16 + c16] = (_Float16)e;
                }
            }
#pragma unroll
            for (int off = 1; off < 16; off <<= 1) s += __shfl_xor(s, off, 64);
            if (c16 == 0) sSum[row][w] = s;
        }
    __syncthreads();
    if (tid < 64) {
        float t = 0.f;
#pragma unroll
        for (int j = 0; j < 8; j++) t += sSum[tid][j];
        invSum[qblk * 64 + tid] = 1.f / t;
    }
}

// ---------- attention kernel B: O = P V (banded), from Vt [d][tok] ----------
// grid (4 n-blocks, 256 q-blocks), 512 threads / 8 waves; tile 64 x 256.
// wave: 32 rows x 64 cols (2x4 MFMA tiles).
__global__ __launch_bounds__(512) void pv_kernel(const _Float16* __restrict__ Pg,
                                                 const float* __restrict__ invSum,
                                                 const _Float16* __restrict__ Vt,
                                                 float* __restrict__ out) {
    const int S = 4096, D = 1024, TOK = 16384;
    __shared__ _Float16 sA[2][64 * 32];    // 2 x 4 KB
    __shared__ _Float16 sB[2][256 * 32];   // 2 x 16 KB
    __shared__ float sInvB[64];

    const int tid  = threadIdx.x;
    const int lane = tid & 63;
    const int w    = tid >> 6;
    const int quad = lane >> 4;
    const int c16  = lane & 15;
    const int n0   = blockIdx.x << 8;
    const int qblk = blockIdx.y;
    const int b    = qblk >> 6;
    const int q0   = (qblk & 63) << 6;

    int kstart = q0 - 256; if (kstart < 0) kstart = 0;
    int kend   = q0 + 320; if (kend > S) kend = S;
    const int L = kend - kstart;
    const int nsteps = L >> 5;          // 10..18

    if (tid < 64) sInvB[tid] = invSum[qblk * 64 + tid];

    const int lrow = lane >> 2;
    const int lcol = (lane & 3) * 8;
    const _Float16* Abase = Pg + (long)qblk * 36864 + (w * 16 + lrow) * 576 + lcol;
    const _Float16* Bbase = Vt + (long)(n0 + lrow) * TOK + b * S + kstart + lcol;

    auto stage = [&](int bi, int kc) {
        if (w < 4)
            async_load16(Abase + kc, (char*)sA[bi] + w * 1024);
#pragma unroll
        for (int j = 0; j < 2; j++) {
            int g = j * 8 + w;
            async_load16(Bbase + (long)g * 16 * TOK + kc, (char*)sB[bi] + g * 1024);
        }
    };

    const int wm = (w >> 2) * 32;
    const int wn = (w & 3) * 64;
    floatx4 acc[2][4] = {};

    stage(0, 0);
    for (int s = 0; s < nsteps; s++) {
        const int bi = s & 1;
        __syncthreads();
        if (s + 1 < nsteps) stage(bi ^ 1, (s + 1) * 32);
        half8 aA[2], bB[4];
#pragma unroll
        for (int mt = 0; mt < 2; mt++)
            aA[mt] = *(const half8*)(sA[bi] + (wm + mt * 16 + c16) * 32 + quad * 8);
#pragma unroll
        for (int nt = 0; nt < 4; nt++)
            bB[nt] = *(const half8*)(sB[bi] + (wn + nt * 16 + c16) * 32 + quad * 8);
#pragma unroll
        for (int mt = 0; mt < 2; mt++)
#pragma unroll
            for (int nt = 0; nt < 4; nt++)
                acc[mt][nt] = MFMA16(aA[mt], bB[nt], acc[mt][nt]);
    }

#pragma unroll
    for (int mt = 0; mt < 2; mt++)
#pragma unroll
        for (int nt = 0; nt < 4; nt++)
#pragma unroll
            for (int reg = 0; reg < 4; reg++) {
                int row = wm + mt * 16 + quad * 4 + reg;
                int col = n0 + wn + nt * 16 + c16;
                out[(long)(b * S + q0 + row) * D + col] = acc[mt][nt][reg] * sInvB[row];
            }
}

extern "C" void kernel_launch(void* const* d_in, const int* in_sizes, int n_in,
                              void* d_out, int out_size, void* d_ws, size_t ws_size,
                              hipStream_t stream) {
    const float* X  = (const float*)d_in[0];
    const float* Y  = (const float*)d_in[1];
    const float* Wq = (const float*)d_in[2];
    const float* Wk = (const float*)d_in[3];
    const float* Wv = (const float*)d_in[4];
    float* out = (float*)d_out;

    const long NTOK = 16384, D = 1024;
    // fp16 workspace. Aliases (all stream-ordered safe):
    //   Kh = Yh   (Yh dead after Q-projection)
    //   Pg,invSum over Xh (Xh dead after V-projection; qk_kernel runs after)
    char* p = (char*)d_ws;
    _Float16* Xh  = (_Float16*)p; p += NTOK * D * 2;   // 32 MB
    _Float16* Yh  = (_Float16*)p; p += NTOK * D * 2;   // 32 MB (reused as Kh)
    _Float16* Wqh = (_Float16*)p; p += D * D * 2;      //  2 MB (pre-scaled by 1/32)
    _Float16* Wkh = (_Float16*)p; p += D * D * 2;
    _Float16* Wvh = (_Float16*)p; p += D * D * 2;
    _Float16* Qh  = (_Float16*)p; p += NTOK * D * 2;   // 32 MB
    _Float16* Vt  = (_Float16*)p; p += NTOK * D * 2;   // 32 MB  [D][NTOK]
    _Float16* Kh  = Yh;
    _Float16* Pg  = Xh;                                // 256*64*576*2 = 18.9 MB
    float* invSum = (float*)(Xh + 256l * 64 * 576);    // 64 KB, still inside Xh

    const int nT = (int)(NTOK * D);
    const int nW = (int)(D * D);
    cvt_kernel<<<nT / 2048, 256, 0, stream>>>(X, Xh, nT, 1.f);
    cvt_kernel<<<nT / 2048, 256, 0, stream>>>(Y, Yh, nT, 1.f);
    cvt_kernel<<<nW / 2048, 256, 0, stream>>>(Wq, Wqh, nW, 0.03125f);  // fold 1/sqrt(1024)
    cvt_kernel<<<nW / 2048, 256, 0, stream>>>(Wk, Wkh, nW, 1.f);
    cvt_kernel<<<nW / 2048, 256, 0, stream>>>(Wv, Wvh, nW, 1.f);

    // Q = Y Wq^T (scaled), K = X Wk^T, Vt = Wv X^T
    gemm_bt<<<dim3(1024 / 128, 16384 / 128), 256, 0, stream>>>(Yh, Wqh, Qh, 16384, 1024, 1024);
    gemm_bt<<<dim3(1024 / 128, 16384 / 128), 256, 0, stream>>>(Xh, Wkh, Kh, 16384, 1024, 1024);
    gemm_bt<<<dim3(16384 / 128, 1024 / 128), 256, 0, stream>>>(Wvh, Xh, Vt, 1024, 16384, 1024);

    qk_kernel<<<dim3(256), 512, 0, stream>>>(Qh, Kh, Pg, invSum);
    pv_kernel<<<dim3(4, 256), 512, 0, stream>>>(Pg, invSum, Vt, out);
}